// Round 19
// baseline (526.539 us; speedup 1.0000x reference)
//
#include <hip/hip_runtime.h>
#include <math.h>

// TransFusionHead anchor matching — round 19: cleanup.
// r18 (term-major MFMA) confirmed chain-stall theory: util 54->59, conv1
// 207->195us. This round: fuse gather_qf into topk (pos/label via LDS,
// 2 blocks gather their own 200x128 query_feat from X2 hi+lo) — one fewer
// launch, no iws round-trip. Conv path = r18 best-known config.

#define HW 180
#define NPIX 32400
#define NCLS 10
#define NPROP 200
#define HID 128
#define TDIM 60
#define NBIG (NCLS*NPIX)

#define TH_LO  (-0.9915981193)
#define TH_STEP (0.1789675812)

__constant__ float c_anchors[10][3] = {
  {4.63f,1.97f,1.74f},{6.93f,2.51f,2.84f},{6.37f,2.85f,3.19f},{10.5f,2.94f,3.47f},
  {12.29f,2.9f,3.87f},{0.5f,2.53f,0.98f},{2.11f,0.77f,1.47f},{1.7f,0.6f,1.28f},
  {0.73f,0.67f,1.77f},{0.41f,0.41f,1.07f}};

using f16x8 = _Float16 __attribute__((ext_vector_type(8)));
using f16x4 = _Float16 __attribute__((ext_vector_type(4)));
using f32x4 = float    __attribute__((ext_vector_type(4)));

#define GLD_LDS16(g, l) __builtin_amdgcn_global_load_lds( \
    (__attribute__((address_space(1))) void*)(g), \
    (__attribute__((address_space(3))) void*)(l), 16, 0, 0)

// ---------- merged prep ----------
__device__ __forceinline__ void w_tr(const float* __restrict__ w, _Float16* __restrict__ dst,
                                     int CIN, int KS, int HALVES, int cout, int i) {
  int N = HALVES * KS * 36864;
  if (i >= N) return;
  int j = i & 7;
  int lane = (i >> 3) & 63;
  int mf = (i >> 9) & 3;
  int rest = i >> 11;
  int tsl = rest % 9; rest /= 9;
  int t = (tsl % 3) * 3 + (tsl / 3);
  int plane = rest & 1; rest >>= 1;
  int ks = rest % KS; int h = rest / KS;
  int co = h * 64 + mf * 16 + (lane & 15);
  int ch = ks * 32 + (lane >> 4) * 8 + j;
  float v = (co < cout) ? w[((size_t)co * CIN + ch) * 9 + t] : 0.f;
  _Float16 hi = (_Float16)v;
  dst[i] = plane ? (_Float16)(v - (float)hi) : hi;
}

__global__ __launch_bounds__(256)
void prep_kernel(const float* __restrict__ w_shared, const float* __restrict__ w_bb,
                 const float* __restrict__ w_hm, const float* __restrict__ feats,
                 _Float16* __restrict__ W1, _Float16* __restrict__ W2,
                 _Float16* __restrict__ W3, _Float16* __restrict__ X1,
                 float* __restrict__ out_sims, int* __restrict__ cnt) {
  int bid = blockIdx.x;
  const int tid = threadIdx.x;
  if (bid < 4608) { w_tr(w_shared, W1, 512, 16, 2, 128, bid * 256 + tid); return; }
  bid -= 4608;
  if (bid < 1152) { w_tr(w_bb, W2, 128, 4, 2, 128, bid * 256 + tid); return; }
  bid -= 1152;
  if (bid < 576)  { w_tr(w_hm, W3, 128, 4, 1, 60, bid * 256 + tid); return; }
  bid -= 576;
  if (bid < 4064) {
    int px = (bid % 127) * 256 + tid;
    int bks = bid / 127; int b = bks >> 4; int ks = bks & 15;
    if (px >= NPIX) return;
    const float* src = feats + ((size_t)(b * 512 + ks * 32)) * NPIX + px;
    float v[32];
#pragma unroll
    for (int c = 0; c < 32; ++c) v[c] = src[(size_t)c * NPIX];
    f16x8 hv[4], lv[4];
#pragma unroll
    for (int c = 0; c < 32; ++c) {
      _Float16 h = (_Float16)v[c];
      hv[c >> 3][c & 7] = h;
      lv[c >> 3][c & 7] = (_Float16)(v[c] - (float)h);
    }
    size_t ob = ((size_t)(b * 16 + ks) * NPIX + px) * 32;
#pragma unroll
    for (int i = 0; i < 4; ++i) {
      *(f16x8*)(X1 + ob + i * 8) = hv[i];
      *(f16x8*)(X1 + 33177600u + ob + i * 8) = lv[i];
    }
    return;
  }
  if (tid < 100) {
    int i = tid / 10, j = tid % 10;
    float r = 1.f;
#pragma unroll
    for (int d = 0; d < 3; ++d) {
      float ai = c_anchors[i][d], aj = c_anchors[j][d];
      r *= fminf(ai, aj) / fmaxf(ai, aj);
    }
    out_sims[tid] = r;
  }
  if (tid == 128) { cnt[0] = 0; cnt[1] = 0; }
}

// ---------- split-fp16 MFMA conv3x3, tile 16x12 px x 64 co (r18 config) ----------
template<int KS, int EPI>
__global__ __launch_bounds__(256, 2)
void conv_mfma(const _Float16* __restrict__ X, const _Float16* __restrict__ W,
               const float* __restrict__ p0, const float* __restrict__ p1,
               float* __restrict__ out0, _Float16* __restrict__ outX,
               const float* __restrict__ thr_scale, const float* __restrict__ logit_scale,
               const float* __restrict__ logit_bias, const float* __restrict__ anchor_vecs) {
  constexpr unsigned XPS = 2u * KS * NPIX * 32;   // f16 per activation plane
  constexpr bool DBUF = (EPI != 2);
  extern __shared__ _Float16 dlds[];
  _Float16* lds_x = dlds;
  _Float16* wA = dlds + 16128;
  _Float16* wB = dlds + 28416;
  float* lds_av = (float*)(dlds + 28416);

  // --- XCD-aware swizzle ---
  const int hwid = blockIdx.x + 12 * blockIdx.y + 180 * blockIdx.z;
  const int xk = hwid & 7, xj = hwid >> 3;
  int zz, ii;
  if (EPI != 2) { zz = xk >> 1; ii = (xk & 1) * 90 + xj; }   // 720 = 8 x 90
  else          { zz = xk >> 2; ii = (xk & 3) * 45 + xj; }   // 360 = 8 x 45
  const int x0 = (ii % 12) * 16;
  const int y0 = (ii / 12) * 12;
  const int b  = (EPI == 2) ? zz : (zz >> 1);
  const int h  = (EPI == 2) ? 0 : (zz & 1);

  const int tid = threadIdx.x;
  const int wave = tid >> 6;
  const int lane = tid & 63;
  const int xl = lane & 15, kg = lane >> 4;

  {
    unsigned* p = (unsigned*)lds_x;
    for (int i = tid; i < 8064; i += 256) p[i] = 0u;
    if (EPI == 2)
      for (int i = tid; i < 600; i += 256) lds_av[i] = anchor_vecs[i];
  }

  unsigned offs[8]; unsigned okb = 0;
#pragma unroll
  for (int s = 0; s < 8; ++s) {
    int inst = wave + 4 * s;
    int c = inst * 64 + lane;
    bool valid = (c < 2016);
    int plane = (c >= 1008) ? 1 : 0;
    int cc = c - plane * 1008;
    int px = cc >> 2, q = cc & 3;
    int r = px / 18, xx = px - r * 18;
    int gy = y0 - 1 + r, gx = x0 - 1 + xx;
    bool ok = valid && ((unsigned)gy < 180u) && ((unsigned)gx < 180u);
    offs[s] = ok ? ((unsigned)((b * KS) * NPIX + gy * 180 + gx) * 32u + (unsigned)q * 8u
                    + (unsigned)plane * XPS) : 0u;
    okb |= (ok ? 1u : 0u) << s;
  }

  f32x4 acc[4][3];
#pragma unroll
  for (int mf = 0; mf < 4; ++mf)
#pragma unroll
    for (int f = 0; f < 3; ++f) acc[mf][f] = (f32x4){0.f, 0.f, 0.f, 0.f};

  auto HOIST = [&](int g, f16x8* bfh, f16x8* bfl) {
#pragma unroll
    for (int rr = 0; rr < 5; ++rr) {
      int lo = ((3 * wave + rr) * 18 + xl + g) * 32 + kg * 8;
      bfh[rr] = *(const f16x8*)(lds_x + lo);
      bfl[rr] = *(const f16x8*)(lds_x + 8064 + lo);
    }
  };
  auto MFMAG = [&](const _Float16* wbuf, const f16x8* bfh, const f16x8* bfl) {
    __builtin_amdgcn_s_setprio(1);
#pragma unroll
    for (int ky = 0; ky < 3; ++ky) {
      const _Float16* wt = wbuf + ky * 2048 + lane * 8;
      f16x8 ah[4], al[4];
#pragma unroll
      for (int mf = 0; mf < 4; ++mf) {
        ah[mf] = *(const f16x8*)(wt + mf * 512);
        al[mf] = *(const f16x8*)(wt + 6144 + mf * 512);
      }
#pragma unroll
      for (int mf = 0; mf < 4; ++mf)
#pragma unroll
        for (int f = 0; f < 3; ++f)
          acc[mf][f] = __builtin_amdgcn_mfma_f32_16x16x32_f16(ah[mf], bfh[f + ky], acc[mf][f], 0, 0, 0);
#pragma unroll
      for (int mf = 0; mf < 4; ++mf)
#pragma unroll
        for (int f = 0; f < 3; ++f)
          acc[mf][f] = __builtin_amdgcn_mfma_f32_16x16x32_f16(ah[mf], bfl[f + ky], acc[mf][f], 0, 0, 0);
#pragma unroll
      for (int mf = 0; mf < 4; ++mf)
#pragma unroll
        for (int f = 0; f < 3; ++f)
          acc[mf][f] = __builtin_amdgcn_mfma_f32_16x16x32_f16(al[mf], bfh[f + ky], acc[mf][f], 0, 0, 0);
    }
    __builtin_amdgcn_s_setprio(0);
  };
  auto COMPUTE = [&](int g, const _Float16* wbuf) {
    f16x8 bfh[5], bfl[5];
    HOIST(g, bfh, bfl);
    MFMAG(wbuf, bfh, bfl);
  };
  auto WDMA = [&](const _Float16* gw, int g, _Float16* wbuf) {
#pragma unroll
    for (int s = 0; s < 6; ++s) {
      int c2 = wave + 4 * s;
      int pl = c2 / 12, idx = c2 - pl * 12;
      GLD_LDS16(gw + pl * 18432 + g * 6144 + idx * 512 + lane * 8,
                wbuf + pl * 6144 + idx * 512);
    }
  };
  auto XDMA = [&](unsigned kof) {
#pragma unroll
    for (int s = 0; s < 8; ++s) {
      if (okb & (1u << s))
        GLD_LDS16(X + (size_t)(offs[s] + kof), lds_x + (wave + 4 * s) * 512);
    }
  };

  const _Float16* gwb = W + (size_t)(h * KS) * 36864;
  if (DBUF) {
    XDMA(0);
    WDMA(gwb, 0, wA);
    __syncthreads();
    _Float16* Pm = wA;
    _Float16* Qm = wB;
    for (int ks = 0; ks < KS; ++ks) {
      const _Float16* gw = gwb + (size_t)ks * 36864;
      WDMA(gw, 1, Qm);
      COMPUTE(0, Pm);
      __syncthreads();
      WDMA(gw, 2, Pm);
      COMPUTE(1, Qm);
      __syncthreads();
      f16x8 bh2[5], bl2[5];
      HOIST(2, bh2, bl2);
      __syncthreads();
      if (ks + 1 < KS) {
        XDMA((unsigned)(ks + 1) * (NPIX * 32u));
        WDMA(gw + 36864, 0, Qm);
      }
      MFMAG(Pm, bh2, bl2);
      if (ks + 1 < KS) __syncthreads();
      _Float16* t = Pm; Pm = Qm; Qm = t;
    }
  } else {
    for (int ks = 0; ks < KS; ++ks) {
      const unsigned kof = (unsigned)ks * (NPIX * 32u);
      const _Float16* gw = gwb + (size_t)ks * 36864;
#pragma unroll
      for (int g = 0; g < 3; ++g) {
        __syncthreads();
        if (g == 0) XDMA(kof);
        WDMA(gw, g, wA);
        __syncthreads();
        COMPUTE(g, wA);
      }
    }
  }

  // ---- epilogue ----
  const int x = x0 + xl;
  if (EPI != 2) {
    if (x >= HW) return;
#pragma unroll
    for (int mf = 0; mf < 4; ++mf) {
      const int cobase = h * 64 + mf * 16 + kg * 4;
      f32x4 q0 = *(const f32x4*)(p0 + cobase);
      f32x4 q1 = (EPI == 1) ? *(const f32x4*)(p1 + cobase) : (f32x4){0.f,0.f,0.f,0.f};
#pragma unroll
      for (int f = 0; f < 3; ++f) {
        const int y = y0 + 3 * wave + f;
        const int kso = cobase >> 5, c32 = cobase & 31;
        size_t nidx = ((size_t)(b * 4 + kso) * NPIX + (size_t)y * 180 + x) * 32 + c32;
        f16x4 h4, l4;
        if (EPI == 0) {
#pragma unroll
          for (int r = 0; r < 4; ++r) {
            float z = acc[mf][f][r] + q0[r];
            _Float16 hh = (_Float16)z;
            h4[r] = hh;
            l4[r] = (_Float16)(z - (float)hh);
          }
        } else {
#pragma unroll
          for (int r = 0; r < 4; ++r) {
            float z = fmaf(acc[mf][f][r], q0[r], q1[r]);
            z = fmaxf(z, 0.f);
            _Float16 hh = (_Float16)z;
            h4[r] = hh;
            l4[r] = (_Float16)(z - (float)hh);
          }
        }
        *(f16x4*)(outX + nidx) = h4;
        *(f16x4*)(outX + 8294400u + nidx) = l4;
      }
    }
  } else {
    const float s  = thr_scale[0];
    const float ls = logit_scale[0];
    const float lb = logit_bias[0];
    float bh4[4][4], th4[4][4];
    bool vmask[4];
#pragma unroll
    for (int mf = 0; mf < 4; ++mf) {
      const int cb = mf * 16 + kg * 4;
      vmask[mf] = (cb < TDIM);
#pragma unroll
      for (int r = 0; r < 4; ++r) {
        bh4[mf][r] = vmask[mf] ? p0[cb + r] : 0.f;
        th4[mf][r] = (float)(TH_LO + (double)((cb + r) % 20) * TH_STEP);
      }
    }
#pragma unroll
    for (int f = 0; f < 3; ++f) {
      const int y = y0 + 3 * wave + f;
      float v[4][4];
      float s2 = 0.f;
#pragma unroll
      for (int mf = 0; mf < 4; ++mf)
#pragma unroll
        for (int r = 0; r < 4; ++r) {
          float z = acc[mf][f][r] + bh4[mf][r];
          float t = (z - th4[mf][r]) * s;
          float vv = vmask[mf] ? 1.f / (1.f + expf(-t)) : 0.f;
          v[mf][r] = vv;
          s2 = fmaf(vv, vv, s2);
        }
      s2 += __shfl_xor(s2, 16);
      s2 += __shfl_xor(s2, 32);
      const float rs = 1.f / (1e-8f + sqrtf(s2));
      float hm[10];
#pragma unroll
      for (int k = 0; k < 10; ++k) {
        float d = 0.f;
#pragma unroll
        for (int mf = 0; mf < 4; ++mf) {
          const int cb = mf * 16 + kg * 4;
          f32x4 a = vmask[mf] ? *(const f32x4*)(lds_av + k * TDIM + cb)
                              : (f32x4){0.f, 0.f, 0.f, 0.f};
#pragma unroll
          for (int r = 0; r < 4; ++r) d = fmaf(v[mf][r], a[r], d);
        }
        d += __shfl_xor(d, 16);
        d += __shfl_xor(d, 32);
        hm[k] = 1.f / (1.f + expf(-fmaf(ls, d * rs, lb)));
      }
      if (x < HW) {
#pragma unroll
        for (int j = 0; j < 3; ++j) {
          int k = kg + 4 * j;
          if (k < NCLS)
            out0[((size_t)(b * NCLS + k) * HW + y) * HW + x] = hm[k];
        }
      }
    }
  }
}

// NMS + two-level compaction (LDS atomics, <=2 global atomics per block).
__global__ __launch_bounds__(256)
void nms_kernel(const float* __restrict__ hm, float* __restrict__ ckey,
                int* __restrict__ cidx, int* __restrict__ cnt) {
  __shared__ int lcnt[2];
  __shared__ int lbase[2];
  const int tid = threadIdx.x;
  if (tid < 2) lcnt[tid] = 0;
  __syncthreads();

  int i = blockIdx.x * 256 + tid;
  bool surv = false; float v = 0.f; int bk = 0, p = 0;
  if (i < 2 * NBIG) {
    int x = i % HW; int y = (i / HW) % HW; int plane = i / NPIX;
    v = hm[i];
    float m = v;
#pragma unroll
    for (int dy = -1; dy <= 1; ++dy)
#pragma unroll
      for (int dx = -1; dx <= 1; ++dx) {
        int yy = y + dy, xx = x + dx;
        if ((unsigned)yy < (unsigned)HW && (unsigned)xx < (unsigned)HW)
          m = fmaxf(m, hm[((size_t)plane * NPIX) + yy * HW + xx]);
      }
    if (v == m) {
      surv = true;
      bk = i / NBIG;
      p = atomicAdd(&lcnt[bk], 1);
    }
  }
  __syncthreads();
  if (tid < 2 && lcnt[tid] > 0)
    lbase[tid] = atomicAdd(&cnt[tid], lcnt[tid]);
  __syncthreads();
  if (surv) {
    int slot = lbase[bk] + p;
    ckey[(size_t)bk * NBIG + slot] = v;
    cidx[(size_t)bk * NBIG + slot] = i - bk * NBIG;
  }
}

// topk + fused query_feat gather (from X2 hi/lo planes).
__global__ __launch_bounds__(1024)
void topk_kernel(const float* __restrict__ ckey, const int* __restrict__ cidx,
                 const int* __restrict__ cnt, const float* __restrict__ heatmap,
                 const float* __restrict__ bev_pos, const _Float16* __restrict__ X2,
                 const float* __restrict__ w_enc, float* __restrict__ out) {
  const int b = blockIdx.x;
  const int tid = threadIdx.x;
  const float* keys = ckey + (size_t)b * NBIG;
  const int* idxs = cidx + (size_t)b * NBIG;

  __shared__ unsigned hist[256];
  __shared__ unsigned sh_prefix;
  __shared__ int sh_want, sh_n;
  __shared__ int cntGT, cntTie;
  __shared__ unsigned gt_key[256], gt_idx[256];
  __shared__ unsigned tie_idx[2048];
  __shared__ int sh_pos[NPROP];
  __shared__ int sh_lab[NPROP];

  if (tid == 0) sh_n = cnt[b];
  __syncthreads();
  const int n = sh_n;

  unsigned prefix = 0; int want = NPROP;
  for (int shift = 24; shift >= 0; shift -= 8) {
    if (tid < 256) hist[tid] = 0u;
    __syncthreads();
    for (int i = tid; i < n; i += 1024) {
      unsigned k = __float_as_uint(keys[i]);
      bool match = (shift == 24) || ((k >> (shift + 8)) == (prefix >> (shift + 8)));
      if (match) atomicAdd(&hist[(k >> shift) & 255], 1u);
    }
    __syncthreads();
    if (tid == 0) {
      int cum = 0; int bsel = 0; sh_want = want;
      for (int bin = 255; bin >= 0; --bin) {
        cum += (int)hist[bin];
        if (cum >= want) { bsel = bin; sh_want = want - (cum - (int)hist[bin]); break; }
      }
      sh_prefix = prefix | ((unsigned)bsel << shift);
      cntGT = 0; cntTie = 0;
    }
    __syncthreads();
    prefix = sh_prefix; want = sh_want;
    __syncthreads();
  }
  const unsigned T = prefix;

  for (int i = tid; i < n; i += 1024) {
    unsigned k = __float_as_uint(keys[i]);
    if (k > T) {
      int p = atomicAdd(&cntGT, 1);
      if (p < 256) { gt_key[p] = k; gt_idx[p] = (unsigned)idxs[i]; }
    } else if (k == T) {
      int p = atomicAdd(&cntTie, 1);
      if (p < 2048) tie_idx[p] = (unsigned)idxs[i];
    }
  }
  __syncthreads();
  const int nGT = min(cntGT, 256);
  const int nTie = min(cntTie, 2048);

  for (int i = tid; i < 256; i += 1024)
    if (i >= nGT) { gt_key[i] = 0u; gt_idx[i] = 0xFFFFFFFFu; }
  for (int i = tid; i < 2048; i += 1024)
    if (i >= nTie) tie_idx[i] = 0xFFFFFFFFu;
  __syncthreads();

  for (int k2 = 2; k2 <= 256; k2 <<= 1) {
    for (int j = k2 >> 1; j > 0; j >>= 1) {
      for (int i = tid; i < 256; i += 1024) {
        int ixj = i ^ j;
        if (ixj > i) {
          unsigned ka = gt_key[i], kb = gt_key[ixj];
          unsigned ia = gt_idx[i], ib = gt_idx[ixj];
          bool firstA = (ka > kb) || (ka == kb && ia < ib);
          bool up = ((i & k2) == 0);
          if (up ? !firstA : firstA) {
            gt_key[i] = kb; gt_key[ixj] = ka;
            gt_idx[i] = ib; gt_idx[ixj] = ia;
          }
        }
      }
      __syncthreads();
    }
  }
  for (int k2 = 2; k2 <= 2048; k2 <<= 1) {
    for (int j = k2 >> 1; j > 0; j >>= 1) {
      for (int i = tid; i < 2048; i += 1024) {
        int ixj = i ^ j;
        if (ixj > i) {
          unsigned ia = tie_idx[i], ib = tie_idx[ixj];
          bool firstA = ia < ib;
          bool up = ((i & k2) == 0);
          if (up ? !firstA : firstA) { tie_idx[i] = ib; tie_idx[ixj] = ia; }
        }
      }
      __syncthreads();
    }
  }

  for (int r = tid; r < NPROP; r += 1024) {
    unsigned idx; float score;
    if (r < nGT) { idx = gt_idx[r]; score = __uint_as_float(gt_key[r]); }
    else         { idx = tie_idx[r - nGT]; score = __uint_as_float(T); }
    int label = (int)(idx / NPIX);
    int pos = (int)(idx - (unsigned)label * NPIX);
    out[648000 + b * NPROP + r] = score;
    out[648400 + b * NPROP + r] = (float)label;
    out[700000 + (b * NPROP + r) * 2 + 0] = bev_pos[pos * 2 + 0];
    out[700000 + (b * NPROP + r) * 2 + 1] = bev_pos[pos * 2 + 1];
#pragma unroll
    for (int k = 0; k < NCLS; ++k)
      out[700800 + (b * NCLS + k) * NPROP + r] = heatmap[(size_t)(b * NCLS + k) * NPIX + pos];
    sh_pos[r] = pos;
    sh_lab[r] = label;
  }
  __syncthreads();

  // fused query_feat gather: c outer (coalesced writes over r)
  for (int i = tid; i < HID * NPROP; i += 1024) {
    int r = i % NPROP;
    int c = i / NPROP;
    int pos = sh_pos[r];
    int label = sh_lab[r];
    float la0 = logf(c_anchors[label][0]);
    float la1 = logf(c_anchors[label][1]);
    float la2 = logf(c_anchors[label][2]);
    float dot = w_enc[c * 3 + 0] * la0 + w_enc[c * 3 + 1] * la1 + w_enc[c * 3 + 2] * la2;
    size_t nidx = ((size_t)(b * 4 + (c >> 5)) * NPIX + pos) * 32 + (c & 31);
    float g = (float)X2[nidx] + (float)X2[8294400u + nidx];
    out[648800 + ((size_t)b * HID + c) * NPROP + r] = g + dot;
  }
}

extern "C" void kernel_launch(void* const* d_in, const int* in_sizes, int n_in,
                              void* d_out, int out_size, void* d_ws, size_t ws_size,
                              hipStream_t stream) {
  (void)in_sizes; (void)n_in; (void)out_size; (void)ws_size;
  const float* feats       = (const float*)d_in[0];
  const float* w_shared    = (const float*)d_in[1];
  const float* b_shared    = (const float*)d_in[2];
  const float* w_bb        = (const float*)d_in[3];
  const float* gamma_bb    = (const float*)d_in[4];
  const float* beta_bb     = (const float*)d_in[5];
  const float* w_hm        = (const float*)d_in[6];
  const float* b_hm        = (const float*)d_in[7];
  const float* thr_scale   = (const float*)d_in[8];
  const float* logit_scale = (const float*)d_in[9];
  const float* logit_bias  = (const float*)d_in[10];
  const float* w_enc       = (const float*)d_in[11];
  const float* anchor_vecs = (const float*)d_in[12];
  const float* bev_pos     = (const float*)d_in[13];
  float* out = (float*)d_out;

  float* ws = (float*)d_ws;
  size_t off = 0;
  _Float16* X1 = (_Float16*)(ws + off); off += 33177600;   // 2 planes x 33.18M f16
  _Float16* X2 = (_Float16*)(ws + off); off += 8294400;    // 2 planes x 8.29M f16
  _Float16* X3 = (_Float16*)(ws + off); off += 8294400;    // 2 planes x 8.29M f16
  _Float16* W1 = (_Float16*)(ws + off); off += 589824;
  _Float16* W2 = (_Float16*)(ws + off); off += 147456;
  _Float16* W3 = (_Float16*)(ws + off); off += 73728;
  float* ckey  = ws + off; off += (size_t)2 * NBIG;
  int*   cidx  = (int*)(ws + off); off += (size_t)2 * NBIG;
  int*   cnt   = (int*)(ws + off);

  prep_kernel<<<10401, 256, 0, stream>>>(w_shared, w_bb, w_hm, feats,
                                         W1, W2, W3, X1, out + 704800, cnt);

  const unsigned CONV_LDS = 81408;   // X 32256 + 2x W-group 24576
  const unsigned HEAD_LDS = 59232;   // X 32256 + W-group 24576 + anchors 2400
  dim3 cgrid(12, 15, 4);   // 720 blocks (= 8 XCD x 90)
  conv_mfma<16,0><<<cgrid, 256, CONV_LDS, stream>>>(X1, W1, b_shared, nullptr, nullptr, X2,
                                                    nullptr, nullptr, nullptr, nullptr);
  conv_mfma<4, 1><<<cgrid, 256, CONV_LDS, stream>>>(X2, W2, gamma_bb, beta_bb, nullptr, X3,
                                                    nullptr, nullptr, nullptr, nullptr);
  dim3 hgrid(12, 15, 2);   // 360 blocks (= 8 XCD x 45)
  conv_mfma<4, 2><<<hgrid, 256, HEAD_LDS, stream>>>(X3, W3, b_hm, nullptr, out, nullptr,
                                                    thr_scale, logit_scale, logit_bias,
                                                    anchor_vecs);

  nms_kernel<<<(2*NBIG + 255)/256, 256, 0, stream>>>(out, ckey, cidx, cnt);
  topk_kernel<<<2, 1024, 0, stream>>>(ckey, cidx, cnt, out, bev_pos, X2, w_enc, out);
}

// Round 20
// 505.756 us; speedup vs baseline: 1.0411x; 1.0411x over previous
//
#include <hip/hip_runtime.h>
#include <math.h>

// TransFusionHead anchor matching — round 20: restore r18 best-known (506us).
// r19's topk+gather fusion regressed (526us; conv unchanged) — reverted.
// Config: split-fp16 MFMA convs (term-major order, W dbuf, X prefetch under
// g2 MFMA, XCD swizzle, setprio), fused conv3-head, compacted NMS, radix topk.

#define HW 180
#define NPIX 32400
#define NCLS 10
#define NPROP 200
#define HID 128
#define TDIM 60
#define NBIG (NCLS*NPIX)

#define TH_LO  (-0.9915981193)
#define TH_STEP (0.1789675812)

__constant__ float c_anchors[10][3] = {
  {4.63f,1.97f,1.74f},{6.93f,2.51f,2.84f},{6.37f,2.85f,3.19f},{10.5f,2.94f,3.47f},
  {12.29f,2.9f,3.87f},{0.5f,2.53f,0.98f},{2.11f,0.77f,1.47f},{1.7f,0.6f,1.28f},
  {0.73f,0.67f,1.77f},{0.41f,0.41f,1.07f}};

using f16x8 = _Float16 __attribute__((ext_vector_type(8)));
using f16x4 = _Float16 __attribute__((ext_vector_type(4)));
using f32x4 = float    __attribute__((ext_vector_type(4)));

#define GLD_LDS16(g, l) __builtin_amdgcn_global_load_lds( \
    (__attribute__((address_space(1))) void*)(g), \
    (__attribute__((address_space(3))) void*)(l), 16, 0, 0)

// ---------- merged prep ----------
__device__ __forceinline__ void w_tr(const float* __restrict__ w, _Float16* __restrict__ dst,
                                     int CIN, int KS, int HALVES, int cout, int i) {
  int N = HALVES * KS * 36864;
  if (i >= N) return;
  int j = i & 7;
  int lane = (i >> 3) & 63;
  int mf = (i >> 9) & 3;
  int rest = i >> 11;
  int tsl = rest % 9; rest /= 9;
  int t = (tsl % 3) * 3 + (tsl / 3);
  int plane = rest & 1; rest >>= 1;
  int ks = rest % KS; int h = rest / KS;
  int co = h * 64 + mf * 16 + (lane & 15);
  int ch = ks * 32 + (lane >> 4) * 8 + j;
  float v = (co < cout) ? w[((size_t)co * CIN + ch) * 9 + t] : 0.f;
  _Float16 hi = (_Float16)v;
  dst[i] = plane ? (_Float16)(v - (float)hi) : hi;
}

__global__ __launch_bounds__(256)
void prep_kernel(const float* __restrict__ w_shared, const float* __restrict__ w_bb,
                 const float* __restrict__ w_hm, const float* __restrict__ feats,
                 _Float16* __restrict__ W1, _Float16* __restrict__ W2,
                 _Float16* __restrict__ W3, _Float16* __restrict__ X1,
                 float* __restrict__ out_sims, int* __restrict__ cnt) {
  int bid = blockIdx.x;
  const int tid = threadIdx.x;
  if (bid < 4608) { w_tr(w_shared, W1, 512, 16, 2, 128, bid * 256 + tid); return; }
  bid -= 4608;
  if (bid < 1152) { w_tr(w_bb, W2, 128, 4, 2, 128, bid * 256 + tid); return; }
  bid -= 1152;
  if (bid < 576)  { w_tr(w_hm, W3, 128, 4, 1, 60, bid * 256 + tid); return; }
  bid -= 576;
  if (bid < 4064) {
    int px = (bid % 127) * 256 + tid;
    int bks = bid / 127; int b = bks >> 4; int ks = bks & 15;
    if (px >= NPIX) return;
    const float* src = feats + ((size_t)(b * 512 + ks * 32)) * NPIX + px;
    float v[32];
#pragma unroll
    for (int c = 0; c < 32; ++c) v[c] = src[(size_t)c * NPIX];
    f16x8 hv[4], lv[4];
#pragma unroll
    for (int c = 0; c < 32; ++c) {
      _Float16 h = (_Float16)v[c];
      hv[c >> 3][c & 7] = h;
      lv[c >> 3][c & 7] = (_Float16)(v[c] - (float)h);
    }
    size_t ob = ((size_t)(b * 16 + ks) * NPIX + px) * 32;
#pragma unroll
    for (int i = 0; i < 4; ++i) {
      *(f16x8*)(X1 + ob + i * 8) = hv[i];
      *(f16x8*)(X1 + 33177600u + ob + i * 8) = lv[i];
    }
    return;
  }
  if (tid < 100) {
    int i = tid / 10, j = tid % 10;
    float r = 1.f;
#pragma unroll
    for (int d = 0; d < 3; ++d) {
      float ai = c_anchors[i][d], aj = c_anchors[j][d];
      r *= fminf(ai, aj) / fmaxf(ai, aj);
    }
    out_sims[tid] = r;
  }
  if (tid == 128) { cnt[0] = 0; cnt[1] = 0; }
}

// ---------- split-fp16 MFMA conv3x3, tile 16x12 px x 64 co ----------
template<int KS, int EPI>
__global__ __launch_bounds__(256, 2)
void conv_mfma(const _Float16* __restrict__ X, const _Float16* __restrict__ W,
               const float* __restrict__ p0, const float* __restrict__ p1,
               float* __restrict__ out0, _Float16* __restrict__ outX,
               const float* __restrict__ thr_scale, const float* __restrict__ logit_scale,
               const float* __restrict__ logit_bias, const float* __restrict__ anchor_vecs) {
  constexpr unsigned XPS = 2u * KS * NPIX * 32;   // f16 per activation plane
  constexpr bool DBUF = (EPI != 2);
  extern __shared__ _Float16 dlds[];
  _Float16* lds_x = dlds;
  _Float16* wA = dlds + 16128;
  _Float16* wB = dlds + 28416;
  float* lds_av = (float*)(dlds + 28416);

  // --- XCD-aware swizzle ---
  const int hwid = blockIdx.x + 12 * blockIdx.y + 180 * blockIdx.z;
  const int xk = hwid & 7, xj = hwid >> 3;
  int zz, ii;
  if (EPI != 2) { zz = xk >> 1; ii = (xk & 1) * 90 + xj; }   // 720 = 8 x 90
  else          { zz = xk >> 2; ii = (xk & 3) * 45 + xj; }   // 360 = 8 x 45
  const int x0 = (ii % 12) * 16;
  const int y0 = (ii / 12) * 12;
  const int b  = (EPI == 2) ? zz : (zz >> 1);
  const int h  = (EPI == 2) ? 0 : (zz & 1);

  const int tid = threadIdx.x;
  const int wave = tid >> 6;
  const int lane = tid & 63;
  const int xl = lane & 15, kg = lane >> 4;

  {
    unsigned* p = (unsigned*)lds_x;
    for (int i = tid; i < 8064; i += 256) p[i] = 0u;
    if (EPI == 2)
      for (int i = tid; i < 600; i += 256) lds_av[i] = anchor_vecs[i];
  }

  unsigned offs[8]; unsigned okb = 0;
#pragma unroll
  for (int s = 0; s < 8; ++s) {
    int inst = wave + 4 * s;
    int c = inst * 64 + lane;
    bool valid = (c < 2016);
    int plane = (c >= 1008) ? 1 : 0;
    int cc = c - plane * 1008;
    int px = cc >> 2, q = cc & 3;
    int r = px / 18, xx = px - r * 18;
    int gy = y0 - 1 + r, gx = x0 - 1 + xx;
    bool ok = valid && ((unsigned)gy < 180u) && ((unsigned)gx < 180u);
    offs[s] = ok ? ((unsigned)((b * KS) * NPIX + gy * 180 + gx) * 32u + (unsigned)q * 8u
                    + (unsigned)plane * XPS) : 0u;
    okb |= (ok ? 1u : 0u) << s;
  }

  f32x4 acc[4][3];
#pragma unroll
  for (int mf = 0; mf < 4; ++mf)
#pragma unroll
    for (int f = 0; f < 3; ++f) acc[mf][f] = (f32x4){0.f, 0.f, 0.f, 0.f};

  auto HOIST = [&](int g, f16x8* bfh, f16x8* bfl) {
#pragma unroll
    for (int rr = 0; rr < 5; ++rr) {
      int lo = ((3 * wave + rr) * 18 + xl + g) * 32 + kg * 8;
      bfh[rr] = *(const f16x8*)(lds_x + lo);
      bfl[rr] = *(const f16x8*)(lds_x + 8064 + lo);
    }
  };
  // term-major MFMA: pass over all 12 accumulators per split term.
  auto MFMAG = [&](const _Float16* wbuf, const f16x8* bfh, const f16x8* bfl) {
    __builtin_amdgcn_s_setprio(1);
#pragma unroll
    for (int ky = 0; ky < 3; ++ky) {
      const _Float16* wt = wbuf + ky * 2048 + lane * 8;
      f16x8 ah[4], al[4];
#pragma unroll
      for (int mf = 0; mf < 4; ++mf) {
        ah[mf] = *(const f16x8*)(wt + mf * 512);
        al[mf] = *(const f16x8*)(wt + 6144 + mf * 512);
      }
#pragma unroll
      for (int mf = 0; mf < 4; ++mf)
#pragma unroll
        for (int f = 0; f < 3; ++f)
          acc[mf][f] = __builtin_amdgcn_mfma_f32_16x16x32_f16(ah[mf], bfh[f + ky], acc[mf][f], 0, 0, 0);
#pragma unroll
      for (int mf = 0; mf < 4; ++mf)
#pragma unroll
        for (int f = 0; f < 3; ++f)
          acc[mf][f] = __builtin_amdgcn_mfma_f32_16x16x32_f16(ah[mf], bfl[f + ky], acc[mf][f], 0, 0, 0);
#pragma unroll
      for (int mf = 0; mf < 4; ++mf)
#pragma unroll
        for (int f = 0; f < 3; ++f)
          acc[mf][f] = __builtin_amdgcn_mfma_f32_16x16x32_f16(al[mf], bfh[f + ky], acc[mf][f], 0, 0, 0);
    }
    __builtin_amdgcn_s_setprio(0);
  };
  auto COMPUTE = [&](int g, const _Float16* wbuf) {
    f16x8 bfh[5], bfl[5];
    HOIST(g, bfh, bfl);
    MFMAG(wbuf, bfh, bfl);
  };
  auto WDMA = [&](const _Float16* gw, int g, _Float16* wbuf) {
#pragma unroll
    for (int s = 0; s < 6; ++s) {
      int c2 = wave + 4 * s;
      int pl = c2 / 12, idx = c2 - pl * 12;
      GLD_LDS16(gw + pl * 18432 + g * 6144 + idx * 512 + lane * 8,
                wbuf + pl * 6144 + idx * 512);
    }
  };
  auto XDMA = [&](unsigned kof) {
#pragma unroll
    for (int s = 0; s < 8; ++s) {
      if (okb & (1u << s))
        GLD_LDS16(X + (size_t)(offs[s] + kof), lds_x + (wave + 4 * s) * 512);
    }
  };

  const _Float16* gwb = W + (size_t)(h * KS) * 36864;
  if (DBUF) {
    XDMA(0);
    WDMA(gwb, 0, wA);
    __syncthreads();
    _Float16* Pm = wA;
    _Float16* Qm = wB;
    for (int ks = 0; ks < KS; ++ks) {
      const _Float16* gw = gwb + (size_t)ks * 36864;
      WDMA(gw, 1, Qm);
      COMPUTE(0, Pm);
      __syncthreads();
      WDMA(gw, 2, Pm);
      COMPUTE(1, Qm);
      __syncthreads();
      f16x8 bh2[5], bl2[5];
      HOIST(2, bh2, bl2);
      __syncthreads();
      if (ks + 1 < KS) {
        XDMA((unsigned)(ks + 1) * (NPIX * 32u));
        WDMA(gw + 36864, 0, Qm);
      }
      MFMAG(Pm, bh2, bl2);
      if (ks + 1 < KS) __syncthreads();
      _Float16* t = Pm; Pm = Qm; Qm = t;
    }
  } else {
    for (int ks = 0; ks < KS; ++ks) {
      const unsigned kof = (unsigned)ks * (NPIX * 32u);
      const _Float16* gw = gwb + (size_t)ks * 36864;
#pragma unroll
      for (int g = 0; g < 3; ++g) {
        __syncthreads();
        if (g == 0) XDMA(kof);
        WDMA(gw, g, wA);
        __syncthreads();
        COMPUTE(g, wA);
      }
    }
  }

  // ---- epilogue: C frag col=lane&15 (pixel x), row=kg*4+r (cout) ----
  const int x = x0 + xl;
  if (EPI != 2) {
    if (x >= HW) return;
#pragma unroll
    for (int mf = 0; mf < 4; ++mf) {
      const int cobase = h * 64 + mf * 16 + kg * 4;
      f32x4 q0 = *(const f32x4*)(p0 + cobase);
      f32x4 q1 = (EPI == 1) ? *(const f32x4*)(p1 + cobase) : (f32x4){0.f,0.f,0.f,0.f};
#pragma unroll
      for (int f = 0; f < 3; ++f) {
        const int y = y0 + 3 * wave + f;
        const int kso = cobase >> 5, c32 = cobase & 31;
        size_t nidx = ((size_t)(b * 4 + kso) * NPIX + (size_t)y * 180 + x) * 32 + c32;
        f16x4 h4, l4;
        if (EPI == 0) {
#pragma unroll
          for (int r = 0; r < 4; ++r) {
            float z = acc[mf][f][r] + q0[r];
            _Float16 hh = (_Float16)z;
            h4[r] = hh;
            l4[r] = (_Float16)(z - (float)hh);
          }
        } else {
#pragma unroll
          for (int r = 0; r < 4; ++r) {
            float z = fmaf(acc[mf][f][r], q0[r], q1[r]);
            z = fmaxf(z, 0.f);
            _Float16 hh = (_Float16)z;
            h4[r] = hh;
            l4[r] = (_Float16)(z - (float)hh);
          }
        }
        *(f16x4*)(outX + nidx) = h4;
        *(f16x4*)(outX + 8294400u + nidx) = l4;
      }
    }
  } else {
    const float s  = thr_scale[0];
    const float ls = logit_scale[0];
    const float lb = logit_bias[0];
    float bh4[4][4], th4[4][4];
    bool vmask[4];
#pragma unroll
    for (int mf = 0; mf < 4; ++mf) {
      const int cb = mf * 16 + kg * 4;
      vmask[mf] = (cb < TDIM);
#pragma unroll
      for (int r = 0; r < 4; ++r) {
        bh4[mf][r] = vmask[mf] ? p0[cb + r] : 0.f;
        th4[mf][r] = (float)(TH_LO + (double)((cb + r) % 20) * TH_STEP);
      }
    }
#pragma unroll
    for (int f = 0; f < 3; ++f) {
      const int y = y0 + 3 * wave + f;
      float v[4][4];
      float s2 = 0.f;
#pragma unroll
      for (int mf = 0; mf < 4; ++mf)
#pragma unroll
        for (int r = 0; r < 4; ++r) {
          float z = acc[mf][f][r] + bh4[mf][r];
          float t = (z - th4[mf][r]) * s;
          float vv = vmask[mf] ? 1.f / (1.f + expf(-t)) : 0.f;
          v[mf][r] = vv;
          s2 = fmaf(vv, vv, s2);
        }
      s2 += __shfl_xor(s2, 16);
      s2 += __shfl_xor(s2, 32);
      const float rs = 1.f / (1e-8f + sqrtf(s2));
      float hm[10];
#pragma unroll
      for (int k = 0; k < 10; ++k) {
        float d = 0.f;
#pragma unroll
        for (int mf = 0; mf < 4; ++mf) {
          const int cb = mf * 16 + kg * 4;
          f32x4 a = vmask[mf] ? *(const f32x4*)(lds_av + k * TDIM + cb)
                              : (f32x4){0.f, 0.f, 0.f, 0.f};
#pragma unroll
          for (int r = 0; r < 4; ++r) d = fmaf(v[mf][r], a[r], d);
        }
        d += __shfl_xor(d, 16);
        d += __shfl_xor(d, 32);
        hm[k] = 1.f / (1.f + expf(-fmaf(ls, d * rs, lb)));
      }
      if (x < HW) {
#pragma unroll
        for (int j = 0; j < 3; ++j) {
          int k = kg + 4 * j;
          if (k < NCLS)
            out0[((size_t)(b * NCLS + k) * HW + y) * HW + x] = hm[k];
        }
      }
    }
  }
}

// NMS + two-level compaction (LDS atomics, <=2 global atomics per block).
__global__ __launch_bounds__(256)
void nms_kernel(const float* __restrict__ hm, float* __restrict__ ckey,
                int* __restrict__ cidx, int* __restrict__ cnt) {
  __shared__ int lcnt[2];
  __shared__ int lbase[2];
  const int tid = threadIdx.x;
  if (tid < 2) lcnt[tid] = 0;
  __syncthreads();

  int i = blockIdx.x * 256 + tid;
  bool surv = false; float v = 0.f; int bk = 0, p = 0;
  if (i < 2 * NBIG) {
    int x = i % HW; int y = (i / HW) % HW; int plane = i / NPIX;
    v = hm[i];
    float m = v;
#pragma unroll
    for (int dy = -1; dy <= 1; ++dy)
#pragma unroll
      for (int dx = -1; dx <= 1; ++dx) {
        int yy = y + dy, xx = x + dx;
        if ((unsigned)yy < (unsigned)HW && (unsigned)xx < (unsigned)HW)
          m = fmaxf(m, hm[((size_t)plane * NPIX) + yy * HW + xx]);
      }
    if (v == m) {
      surv = true;
      bk = i / NBIG;
      p = atomicAdd(&lcnt[bk], 1);
    }
  }
  __syncthreads();
  if (tid < 2 && lcnt[tid] > 0)
    lbase[tid] = atomicAdd(&cnt[tid], lcnt[tid]);
  __syncthreads();
  if (surv) {
    int slot = lbase[bk] + p;
    ckey[(size_t)bk * NBIG + slot] = v;
    cidx[(size_t)bk * NBIG + slot] = i - bk * NBIG;
  }
}

__global__ __launch_bounds__(1024)
void topk_kernel(const float* __restrict__ ckey, const int* __restrict__ cidx,
                 const int* __restrict__ cnt, const float* __restrict__ heatmap,
                 const float* __restrict__ bev_pos, float* __restrict__ out,
                 int* __restrict__ iws) {
  const int b = blockIdx.x;
  const int tid = threadIdx.x;
  const float* keys = ckey + (size_t)b * NBIG;
  const int* idxs = cidx + (size_t)b * NBIG;

  __shared__ unsigned hist[256];
  __shared__ unsigned sh_prefix;
  __shared__ int sh_want, sh_n;
  __shared__ int cntGT, cntTie;
  __shared__ unsigned gt_key[256], gt_idx[256];
  __shared__ unsigned tie_idx[2048];

  if (tid == 0) sh_n = cnt[b];
  __syncthreads();
  const int n = sh_n;

  unsigned prefix = 0; int want = NPROP;
  for (int shift = 24; shift >= 0; shift -= 8) {
    if (tid < 256) hist[tid] = 0u;
    __syncthreads();
    for (int i = tid; i < n; i += 1024) {
      unsigned k = __float_as_uint(keys[i]);
      bool match = (shift == 24) || ((k >> (shift + 8)) == (prefix >> (shift + 8)));
      if (match) atomicAdd(&hist[(k >> shift) & 255], 1u);
    }
    __syncthreads();
    if (tid == 0) {
      int cum = 0; int bsel = 0; sh_want = want;
      for (int bin = 255; bin >= 0; --bin) {
        cum += (int)hist[bin];
        if (cum >= want) { bsel = bin; sh_want = want - (cum - (int)hist[bin]); break; }
      }
      sh_prefix = prefix | ((unsigned)bsel << shift);
      cntGT = 0; cntTie = 0;
    }
    __syncthreads();
    prefix = sh_prefix; want = sh_want;
    __syncthreads();
  }
  const unsigned T = prefix;

  for (int i = tid; i < n; i += 1024) {
    unsigned k = __float_as_uint(keys[i]);
    if (k > T) {
      int p = atomicAdd(&cntGT, 1);
      if (p < 256) { gt_key[p] = k; gt_idx[p] = (unsigned)idxs[i]; }
    } else if (k == T) {
      int p = atomicAdd(&cntTie, 1);
      if (p < 2048) tie_idx[p] = (unsigned)idxs[i];
    }
  }
  __syncthreads();
  const int nGT = min(cntGT, 256);
  const int nTie = min(cntTie, 2048);

  for (int i = tid; i < 256; i += 1024)
    if (i >= nGT) { gt_key[i] = 0u; gt_idx[i] = 0xFFFFFFFFu; }
  for (int i = tid; i < 2048; i += 1024)
    if (i >= nTie) tie_idx[i] = 0xFFFFFFFFu;
  __syncthreads();

  for (int k2 = 2; k2 <= 256; k2 <<= 1) {
    for (int j = k2 >> 1; j > 0; j >>= 1) {
      for (int i = tid; i < 256; i += 1024) {
        int ixj = i ^ j;
        if (ixj > i) {
          unsigned ka = gt_key[i], kb = gt_key[ixj];
          unsigned ia = gt_idx[i], ib = gt_idx[ixj];
          bool firstA = (ka > kb) || (ka == kb && ia < ib);
          bool up = ((i & k2) == 0);
          if (up ? !firstA : firstA) {
            gt_key[i] = kb; gt_key[ixj] = ka;
            gt_idx[i] = ib; gt_idx[ixj] = ia;
          }
        }
      }
      __syncthreads();
    }
  }
  for (int k2 = 2; k2 <= 2048; k2 <<= 1) {
    for (int j = k2 >> 1; j > 0; j >>= 1) {
      for (int i = tid; i < 2048; i += 1024) {
        int ixj = i ^ j;
        if (ixj > i) {
          unsigned ia = tie_idx[i], ib = tie_idx[ixj];
          bool firstA = ia < ib;
          bool up = ((i & k2) == 0);
          if (up ? !firstA : firstA) { tie_idx[i] = ib; tie_idx[ixj] = ia; }
        }
      }
      __syncthreads();
    }
  }

  for (int r = tid; r < NPROP; r += 1024) {
    unsigned idx; float score;
    if (r < nGT) { idx = gt_idx[r]; score = __uint_as_float(gt_key[r]); }
    else         { idx = tie_idx[r - nGT]; score = __uint_as_float(T); }
    int label = (int)(idx / NPIX);
    int pos = (int)(idx - (unsigned)label * NPIX);
    out[648000 + b * NPROP + r] = score;
    out[648400 + b * NPROP + r] = (float)label;
    out[700000 + (b * NPROP + r) * 2 + 0] = bev_pos[pos * 2 + 0];
    out[700000 + (b * NPROP + r) * 2 + 1] = bev_pos[pos * 2 + 1];
#pragma unroll
    for (int k = 0; k < NCLS; ++k)
      out[700800 + (b * NCLS + k) * NPROP + r] = heatmap[(size_t)(b * NCLS + k) * NPIX + pos];
    iws[b * NPROP + r] = pos;
    iws[2 * NPROP + b * NPROP + r] = label;
  }
}

// lidar reconstructed from X2 hi+lo f16 planes: [b][4ks][px][32] (+8294400 lo)
__global__ void gather_qf_kernel(const _Float16* __restrict__ X2, const float* __restrict__ w_enc,
                                 const int* __restrict__ iws, float* __restrict__ out_qf) {
  int p = blockIdx.x % NPROP;
  int b = blockIdx.x / NPROP;
  int c = threadIdx.x;
  int pos = iws[b * NPROP + p];
  int label = iws[2 * NPROP + b * NPROP + p];
  float la0 = logf(c_anchors[label][0]);
  float la1 = logf(c_anchors[label][1]);
  float la2 = logf(c_anchors[label][2]);
  float dot = w_enc[c * 3 + 0] * la0 + w_enc[c * 3 + 1] * la1 + w_enc[c * 3 + 2] * la2;
  size_t nidx = ((size_t)(b * 4 + (c >> 5)) * NPIX + pos) * 32 + (c & 31);
  float g = (float)X2[nidx] + (float)X2[8294400u + nidx];
  out_qf[((size_t)b * HID + c) * NPROP + p] = g + dot;
}

extern "C" void kernel_launch(void* const* d_in, const int* in_sizes, int n_in,
                              void* d_out, int out_size, void* d_ws, size_t ws_size,
                              hipStream_t stream) {
  (void)in_sizes; (void)n_in; (void)out_size; (void)ws_size;
  const float* feats       = (const float*)d_in[0];
  const float* w_shared    = (const float*)d_in[1];
  const float* b_shared    = (const float*)d_in[2];
  const float* w_bb        = (const float*)d_in[3];
  const float* gamma_bb    = (const float*)d_in[4];
  const float* beta_bb     = (const float*)d_in[5];
  const float* w_hm        = (const float*)d_in[6];
  const float* b_hm        = (const float*)d_in[7];
  const float* thr_scale   = (const float*)d_in[8];
  const float* logit_scale = (const float*)d_in[9];
  const float* logit_bias  = (const float*)d_in[10];
  const float* w_enc       = (const float*)d_in[11];
  const float* anchor_vecs = (const float*)d_in[12];
  const float* bev_pos     = (const float*)d_in[13];
  float* out = (float*)d_out;

  float* ws = (float*)d_ws;
  size_t off = 0;
  _Float16* X1 = (_Float16*)(ws + off); off += 33177600;   // 2 planes x 33.18M f16
  _Float16* X2 = (_Float16*)(ws + off); off += 8294400;    // 2 planes x 8.29M f16
  _Float16* X3 = (_Float16*)(ws + off); off += 8294400;    // 2 planes x 8.29M f16
  _Float16* W1 = (_Float16*)(ws + off); off += 589824;
  _Float16* W2 = (_Float16*)(ws + off); off += 147456;
  _Float16* W3 = (_Float16*)(ws + off); off += 73728;
  float* ckey  = ws + off; off += (size_t)2 * NBIG;
  int*   cidx  = (int*)(ws + off); off += (size_t)2 * NBIG;
  int*   iws   = (int*)(ws + off); off += 800;
  int*   cnt   = (int*)(ws + off);

  prep_kernel<<<10401, 256, 0, stream>>>(w_shared, w_bb, w_hm, feats,
                                         W1, W2, W3, X1, out + 704800, cnt);

  const unsigned CONV_LDS = 81408;   // X 32256 + 2x W-group 24576
  const unsigned HEAD_LDS = 59232;   // X 32256 + W-group 24576 + anchors 2400
  dim3 cgrid(12, 15, 4);   // 720 blocks (= 8 XCD x 90)
  conv_mfma<16,0><<<cgrid, 256, CONV_LDS, stream>>>(X1, W1, b_shared, nullptr, nullptr, X2,
                                                    nullptr, nullptr, nullptr, nullptr);
  conv_mfma<4, 1><<<cgrid, 256, CONV_LDS, stream>>>(X2, W2, gamma_bb, beta_bb, nullptr, X3,
                                                    nullptr, nullptr, nullptr, nullptr);
  dim3 hgrid(12, 15, 2);   // 360 blocks (= 8 XCD x 45)
  conv_mfma<4, 2><<<hgrid, 256, HEAD_LDS, stream>>>(X3, W3, b_hm, nullptr, out, nullptr,
                                                    thr_scale, logit_scale, logit_bias,
                                                    anchor_vecs);

  nms_kernel<<<(2*NBIG + 255)/256, 256, 0, stream>>>(out, ckey, cidx, cnt);
  topk_kernel<<<2, 1024, 0, stream>>>(ckey, cidx, cnt, out, bev_pos, out, iws);
  gather_qf_kernel<<<2*NPROP, 128, 0, stream>>>(X2, w_enc, iws, out + 648800);
}